// Round 8
// baseline (685.544 us; speedup 1.0000x reference)
//
#include <hip/hip_runtime.h>
#include <cstdint>
#include <cstddef>

typedef unsigned short u16;
typedef unsigned int u32;
typedef short s16x8 __attribute__((ext_vector_type(8)));   // 8 bf16 in 4 VGPRs
typedef float f32x4 __attribute__((ext_vector_type(4)));

// Problem constants: B=4,S=2048 -> T=8192 tokens, D=1024, H=4096, DO=1024, E=8, K=2
#define T_TOK 8192
#define D_IN  1024
#define H_DIM 4096
#define DO_DIM 1024

__device__ __forceinline__ u16 f2bf(float f) {  // RNE f32 -> bf16
    u32 u = __float_as_uint(f);
    return (u16)((u + 0x7FFFu + ((u >> 16) & 1u)) >> 16);
}

__device__ __forceinline__ f32x4 mfma16(s16x8 a, s16x8 b, f32x4 c) {
    return __builtin_amdgcn_mfma_f32_16x16x32_bf16(a, b, c, 0, 0, 0);
}

// async 16B global->LDS (direct DMA, no VGPR round trip)
__device__ __forceinline__ void gload16(const void* g, void* l) {
    __builtin_amdgcn_global_load_lds(
        (const __attribute__((address_space(1))) void*)g,
        (__attribute__((address_space(3))) void*)l,
        16, 0, 0);
}

// ---------------- gate ----------------
__global__ __launch_bounds__(256) void gate_kernel(
    const float* __restrict__ x, const float* __restrict__ gw,
    const float* __restrict__ gb, float* __restrict__ weights_out,
    float* __restrict__ topi_out, int* __restrict__ counts,
    int* __restrict__ tok_list, int* __restrict__ slot_of_tok)
{
    const int t = blockIdx.x;
    const int tid = threadIdx.x;
    __shared__ float red[256][8];
    float p[8];
#pragma unroll
    for (int e = 0; e < 8; ++e) p[e] = 0.f;
    const float* xr = x + ((size_t)t << 10);
    for (int d = tid; d < D_IN; d += 256) {
        float xv = xr[d];
        const f32x4 g0 = *(const f32x4*)(gw + d * 8);
        const f32x4 g1 = *(const f32x4*)(gw + d * 8 + 4);
        p[0] += xv * g0[0]; p[1] += xv * g0[1]; p[2] += xv * g0[2]; p[3] += xv * g0[3];
        p[4] += xv * g1[0]; p[5] += xv * g1[1]; p[6] += xv * g1[2]; p[7] += xv * g1[3];
    }
#pragma unroll
    for (int e = 0; e < 8; ++e) red[tid][e] = p[e];
    __syncthreads();
    for (int s = 128; s > 0; s >>= 1) {
        if (tid < s) {
#pragma unroll
            for (int e = 0; e < 8; ++e) red[tid][e] += red[tid + s][e];
        }
        __syncthreads();
    }
    if (tid == 0) {
        float lg[8];
#pragma unroll
        for (int e = 0; e < 8; ++e) lg[e] = red[0][e] + gb[e];
        int i0 = 0;
        for (int e = 1; e < 8; ++e) if (lg[e] > lg[i0]) i0 = e;   // ties -> lowest idx (matches top_k)
        int i1 = (i0 == 0) ? 1 : 0;
        for (int e = 0; e < 8; ++e) if (e != i0 && lg[e] > lg[i1]) i1 = e;
        float ex = expf(lg[i1] - lg[i0]);          // <= 1
        float p0 = 1.f / (1.f + ex);
        float p1 = ex / (1.f + ex);
#pragma unroll
        for (int e = 0; e < 8; ++e)
            weights_out[t * 8 + e] = (e == i0) ? p0 : ((e == i1) ? p1 : 0.f);
        topi_out[t * 2 + 0] = (float)i0;
        topi_out[t * 2 + 1] = (float)i1;
        int pos0 = atomicAdd(&counts[i0], 1);
        tok_list[(i0 << 13) + pos0] = t;
        slot_of_tok[t * 2 + 0] = (i0 << 13) + pos0;
        int pos1 = atomicAdd(&counts[i1], 1);
        tok_list[(i1 << 13) + pos1] = t;
        slot_of_tok[t * 2 + 1] = (i1 << 13) + pos1;
    }
}

__global__ void zero_counts_kernel(int* c) { if (threadIdx.x < 8) c[threadIdx.x] = 0; }

// exclusive scan of 8 counts -> base[], usage, and DENSE active-row-block table:
// rbt[0] = nrb; rbt[1+i] = (e<<16)|rb  for each active 256-row block of each expert.
// Dense flat block ids spread evenly over all 256 CUs (fixes the mod-256 clustering
// that left 3/4 of CUs idle through r7).
__global__ void scan_kernel(const int* __restrict__ counts, int* __restrict__ base,
                            float* __restrict__ usage_out, int* __restrict__ rbt) {
    if (threadIdx.x == 0) {
        int acc = 0;
        for (int e = 0; e < 8; ++e) {
            base[e] = acc;
            acc += counts[e];
            usage_out[e] = (float)counts[e];
        }
        int nrb = 0;
        for (int e = 0; e < 8; ++e) {
            int nb = (counts[e] + 255) >> 8;
            for (int rb = 0; rb < nb; ++rb) rbt[1 + nrb++] = (e << 16) | rb;
        }
        rbt[0] = nrb;   // <= 72
    }
}

// ---------------- gather: xg[slot][d] = bf16(x[tok][d]) ----------------
__global__ __launch_bounds__(256) void gather_kernel(
    const float* __restrict__ x, const int* __restrict__ counts,
    const int* __restrict__ base, const int* __restrict__ tok_list,
    u16* __restrict__ xg)
{
    const int e = blockIdx.y;
    const int pos = blockIdx.x;
    if (pos >= counts[e]) return;
    const int slot = base[e] + pos;
    const int tok = tok_list[(e << 13) + pos];
    const int d = threadIdx.x * 4;
    float4 v = *(const float4*)(x + ((size_t)tok << 10) + d);
    ushort4 h;
    h.x = f2bf(v.x); h.y = f2bf(v.y); h.z = f2bf(v.z); h.w = f2bf(v.w);
    *(ushort4*)(xg + ((size_t)slot << 10) + d) = h;
}

// ---------------- transpose+cvt ----------------
__global__ __launch_bounds__(256) void transpose_kernel(
    const float* __restrict__ w1, const float* __restrict__ w2,
    u16* __restrict__ w1t, u16* __restrict__ w2t, int chunk, int HC)
{
    const int e = blockIdx.z;
    const int tid = threadIdx.x;
    const int tiles_h = HC >> 6;
    const int ntile1 = 16 * tiles_h;
    int b = blockIdx.x;
    const float* src; u16* dst;
    size_t sstride, dstride;
    int r0, c0;
    if (b < ntile1) {
        int tr = b / tiles_h, tc = b % tiles_h;
        r0 = tr * 64; c0 = tc * 64;
        src = w1 + (size_t)e * D_IN * H_DIM + (size_t)chunk * HC;
        sstride = H_DIM;
        dst = w1t + (size_t)e * HC * D_IN;
        dstride = D_IN;
    } else {
        int tb = b - ntile1;
        int tr = tb / 16, tc = tb % 16;
        r0 = tr * 64; c0 = tc * 64;
        src = w2 + ((size_t)e * H_DIM + (size_t)chunk * HC) * DO_DIM;
        sstride = DO_DIM;
        dst = w2t + (size_t)e * DO_DIM * HC;
        dstride = HC;
    }
    __shared__ u16 tile[64][68];
#pragma unroll
    for (int i = 0; i < 4; ++i) {
        int flat = i * 1024 + tid * 4;
        int rr = flat >> 6, cc = flat & 63;
        float4 v = *(const float4*)(src + (size_t)(r0 + rr) * sstride + c0 + cc);
        ushort4 h4;
        h4.x = f2bf(v.x); h4.y = f2bf(v.y); h4.z = f2bf(v.z); h4.w = f2bf(v.w);
        *(ushort4*)&tile[rr][cc] = h4;
    }
    __syncthreads();
#pragma unroll
    for (int i = 0; i < 4; ++i) {
        int flat = i * 1024 + tid * 4;
        int rr = flat >> 6, cc = flat & 63;
        ushort4 o;
        o.x = tile[cc + 0][rr]; o.y = tile[cc + 1][rr];
        o.z = tile[cc + 2][rr]; o.w = tile[cc + 3][rr];
        *(ushort4*)(dst + (size_t)(c0 + rr) * dstride + r0 + cc) = o;
    }
}

// ====================== 256x256 BK=64 8-phase MFMA GEMM cores (m201 template) ======================
// (unchanged from r7 — see r7 comments; verified correct, 0 bank conflicts)

#define STAGE_A(buf, s, kt) do { \
    char* l_ = (char*)sm + (buf)*65536 + (s)*16384 + wofs; \
    gload16(gA[2*(s)]   + (kt)*128, l_); \
    gload16(gA[2*(s)+1] + (kt)*128, l_ + 8192); } while(0)

#define STAGE_B(buf, s, kt) do { \
    char* l_ = (char*)sm + (buf)*65536 + 32768 + (s)*16384 + wofs; \
    gload16(gB[2*(s)]   + (kt)*128, l_); \
    gload16(gB[2*(s)+1] + (kt)*128, l_ + 8192); } while(0)

#define VMW4 asm volatile("s_waitcnt vmcnt(4)" ::: "memory")
#define NOWAIT do {} while(0)

#define PHASE(buf, q, RB, STAGE_STMT, WAIT_STMT) do { \
    const char* Ab_ = (const char*)sm + (buf)*65536 + (wm << 14); \
    const char* Bb_ = (const char*)sm + (buf)*65536 + 32768 + ((wn >> 1) << 14) + ((wn & 1) << 13); \
    s16x8 a0k0_ = *(const s16x8*)(Ab_ + (q)*4096 +    0 + aofs0); \
    s16x8 a0k1_ = *(const s16x8*)(Ab_ + (q)*4096 +    0 + aofs1); \
    s16x8 a1k0_ = *(const s16x8*)(Ab_ + (q)*4096 + 2048 + aofs0); \
    s16x8 a1k1_ = *(const s16x8*)(Ab_ + (q)*4096 + 2048 + aofs1); \
    if (RB) { \
        bf0[0] = *(const s16x8*)(Bb_ +    0 + aofs0); bf1[0] = *(const s16x8*)(Bb_ +    0 + aofs1); \
        bf0[1] = *(const s16x8*)(Bb_ + 2048 + aofs0); bf1[1] = *(const s16x8*)(Bb_ + 2048 + aofs1); \
        bf0[2] = *(const s16x8*)(Bb_ + 4096 + aofs0); bf1[2] = *(const s16x8*)(Bb_ + 4096 + aofs1); \
        bf0[3] = *(const s16x8*)(Bb_ + 6144 + aofs0); bf1[3] = *(const s16x8*)(Bb_ + 6144 + aofs1); \
    } \
    STAGE_STMT; \
    WAIT_STMT; \
    __builtin_amdgcn_sched_barrier(0); \
    __builtin_amdgcn_s_barrier(); \
    asm volatile("s_waitcnt lgkmcnt(0)" ::: "memory"); \
    __builtin_amdgcn_sched_barrier(0); \
    __builtin_amdgcn_s_setprio(1); \
    acc[(q)*2+0][0] = mfma16(a0k0_, bf0[0], acc[(q)*2+0][0]); \
    acc[(q)*2+1][0] = mfma16(a1k0_, bf0[0], acc[(q)*2+1][0]); \
    acc[(q)*2+0][1] = mfma16(a0k0_, bf0[1], acc[(q)*2+0][1]); \
    acc[(q)*2+1][1] = mfma16(a1k0_, bf0[1], acc[(q)*2+1][1]); \
    acc[(q)*2+0][2] = mfma16(a0k0_, bf0[2], acc[(q)*2+0][2]); \
    acc[(q)*2+1][2] = mfma16(a1k0_, bf0[2], acc[(q)*2+1][2]); \
    acc[(q)*2+0][3] = mfma16(a0k0_, bf0[3], acc[(q)*2+0][3]); \
    acc[(q)*2+1][3] = mfma16(a1k0_, bf0[3], acc[(q)*2+1][3]); \
    acc[(q)*2+0][0] = mfma16(a0k1_, bf1[0], acc[(q)*2+0][0]); \
    acc[(q)*2+1][0] = mfma16(a1k1_, bf1[0], acc[(q)*2+1][0]); \
    acc[(q)*2+0][1] = mfma16(a0k1_, bf1[1], acc[(q)*2+0][1]); \
    acc[(q)*2+1][1] = mfma16(a1k1_, bf1[1], acc[(q)*2+1][1]); \
    acc[(q)*2+0][2] = mfma16(a0k1_, bf1[2], acc[(q)*2+0][2]); \
    acc[(q)*2+1][2] = mfma16(a1k1_, bf1[2], acc[(q)*2+1][2]); \
    acc[(q)*2+0][3] = mfma16(a0k1_, bf1[3], acc[(q)*2+0][3]); \
    acc[(q)*2+1][3] = mfma16(a1k1_, bf1[3], acc[(q)*2+1][3]); \
    __builtin_amdgcn_s_setprio(0); \
    __builtin_amdgcn_sched_barrier(0); \
    __builtin_amdgcn_s_barrier(); } while(0)

#define GEMM_PIPE(NTV) do { \
    STAGE_B(0, 0, 0); STAGE_B(0, 1, 0); \
    STAGE_A(0, 0, 0); STAGE_A(0, 1, 0); \
    STAGE_B(1, 0, 1); STAGE_B(1, 1, 1); \
    asm volatile("s_waitcnt vmcnt(4)" ::: "memory"); \
    __builtin_amdgcn_sched_barrier(0); \
    __builtin_amdgcn_s_barrier(); \
    __builtin_amdgcn_sched_barrier(0); \
    const int nh_ = (NTV) >> 1; \
    _Pragma("unroll 1") \
    for (int it_ = 0; it_ < nh_; ++it_) { \
        const int t_ = it_ << 1; \
        const int kA1_ = t_ + 1; \
        const int kB2_ = (t_ + 2 < (NTV)) ? t_ + 2 : (NTV) - 1; \
        const int kB3_ = (t_ + 3 < (NTV)) ? t_ + 3 : (NTV) - 1; \
        PHASE(0, 0, 1, STAGE_A(1, 0, kA1_), NOWAIT); \
        PHASE(0, 1, 0, STAGE_A(1, 1, kA1_), NOWAIT); \
        PHASE(0, 2, 0, STAGE_B(0, 0, kB2_), NOWAIT); \
        PHASE(0, 3, 0, STAGE_B(0, 1, kB2_), VMW4); \
        PHASE(1, 0, 1, STAGE_A(0, 0, kB2_), NOWAIT); \
        PHASE(1, 1, 0, STAGE_A(0, 1, kB2_), NOWAIT); \
        PHASE(1, 2, 0, STAGE_B(1, 0, kB3_), NOWAIT); \
        PHASE(1, 3, 0, STAGE_B(1, 1, kB3_), VMW4); \
    } \
    asm volatile("s_waitcnt vmcnt(0)" ::: "memory"); \
    __builtin_amdgcn_sched_barrier(0); } while(0)

// ---------------- GEMM1: hbuf[slot][hh] = relu(xg[slot] @ w1t[e] + b1[e]), bf16 out ----------------
__global__ __launch_bounds__(512) void gemm1_kernel(
    const u16* __restrict__ xg, const u16* __restrict__ w1t,
    const float* __restrict__ b1, u16* __restrict__ hbuf,
    const int* __restrict__ counts, const int* __restrict__ base,
    const int* __restrict__ rbt, int chunk, int HC)
{
    const int nrb = rbt[0];
    if (blockIdx.y >= nrb) return;
    const int ent = rbt[1 + blockIdx.y];
    const int e = ent >> 16;
    const int row0 = (ent & 0xffff) << 8;
    const int n_e = counts[e];
    const int sbase = base[e];
    const int col0 = blockIdx.x << 8;
    const int tid = threadIdx.x;
    const int lane = tid & 63;
    const int wv = tid >> 6;
    const int wm = wv >> 2;
    const int wn = wv & 3;

    __shared__ char sm[131072];

    // stage source addresses (per lane), inverse-swizzled
    const int srow = tid >> 3;
    const int scb  = ((tid & 7) << 4) ^ ((srow & 7) << 4);
    const char* gA[4]; const char* gB[4];
#pragma unroll
    for (int i = 0; i < 4; ++i) {
        int slot = sbase + row0 + i * 64 + srow;
        slot = slot < 16383 ? slot : 16383;                      // clamp tail (guarded at C-write)
        gA[i] = (const char*)xg + ((size_t)slot << 11) + scb;
        int hrow = col0 + i * 64 + srow;                         // < HC
        gB[i] = (const char*)w1t + (((size_t)e * HC + hrow) << 11) + scb;
    }
    const int wofs = __builtin_amdgcn_readfirstlane((tid >> 6) << 10);

    // fragment read offsets (swizzled)
    const int rA = lane & 15;
    const int ko = (lane >> 4) << 4;
    const int sx = (lane & 7) << 4;
    const int aofs0 = rA * 128 + (ko ^ sx);
    const int aofs1 = rA * 128 + ((64 + ko) ^ sx);

    f32x4 acc[8][4];
#pragma unroll
    for (int m = 0; m < 8; ++m)
#pragma unroll
        for (int n = 0; n < 4; ++n) acc[m][n] = f32x4{0.f, 0.f, 0.f, 0.f};
    s16x8 bf0[4], bf1[4];

    GEMM_PIPE(16);    // NT = D_IN/64

    // epilogue: bias + relu + cvt, guarded rows
    const int crow = (wm << 7) + ((lane >> 4) << 2);
    const int ccol = (wn << 6) + (lane & 15);
    float bias_n[4];
#pragma unroll
    for (int n = 0; n < 4; ++n)
        bias_n[n] = b1[(e << 12) + chunk * HC + col0 + ccol + n * 16];
#pragma unroll
    for (int m = 0; m < 8; ++m) {
#pragma unroll
        for (int j = 0; j < 4; ++j) {
            int r = row0 + crow + m * 16 + j;
            if (r < n_e) {
                u16* dst = hbuf + (size_t)(sbase + r) * HC + col0;
#pragma unroll
                for (int n = 0; n < 4; ++n) {
                    float v = acc[m][n][j] + bias_n[n];
                    v = v > 0.f ? v : 0.f;
                    dst[ccol + n * 16] = f2bf(v);
                }
            }
        }
    }
}

// ---------------- GEMM2: eo[slot][o] (+)= hbuf[slot] @ w2t[e] (+ b2 on chunk 0), f32 out ----------------
__global__ __launch_bounds__(512) void gemm2_kernel(
    const u16* __restrict__ hbuf, const u16* __restrict__ w2t,
    const float* __restrict__ b2, float* __restrict__ eo,
    const int* __restrict__ counts, const int* __restrict__ base,
    const int* __restrict__ rbt, int chunk, int HC)
{
    const int nrb = rbt[0];
    if (blockIdx.y >= nrb) return;
    const int ent = rbt[1 + blockIdx.y];
    const int e = ent >> 16;
    const int row0 = (ent & 0xffff) << 8;
    const int n_e = counts[e];
    const int sbase = base[e];
    const int col0 = blockIdx.x << 8;
    const int tid = threadIdx.x;
    const int lane = tid & 63;
    const int wv = tid >> 6;
    const int wm = wv >> 2;
    const int wn = wv & 3;

    __shared__ char sm[131072];

    const int srow = tid >> 3;
    const int scb  = ((tid & 7) << 4) ^ ((srow & 7) << 4);
    const char* gA[4]; const char* gB[4];
#pragma unroll
    for (int i = 0; i < 4; ++i) {
        int slot = sbase + row0 + i * 64 + srow;
        slot = slot < 16383 ? slot : 16383;
        gA[i] = (const char*)hbuf + (((size_t)slot * HC) << 1) + scb;
        int orow = col0 + i * 64 + srow;                          // < 1024
        gB[i] = (const char*)w2t + ((((size_t)(e << 10) + orow) * HC) << 1) + scb;
    }
    const int wofs = __builtin_amdgcn_readfirstlane((tid >> 6) << 10);

    const int rA = lane & 15;
    const int ko = (lane >> 4) << 4;
    const int sx = (lane & 7) << 4;
    const int aofs0 = rA * 128 + (ko ^ sx);
    const int aofs1 = rA * 128 + ((64 + ko) ^ sx);

    f32x4 acc[8][4];
#pragma unroll
    for (int m = 0; m < 8; ++m)
#pragma unroll
        for (int n = 0; n < 4; ++n) acc[m][n] = f32x4{0.f, 0.f, 0.f, 0.f};
    s16x8 bf0[4], bf1[4];

    const int NT = HC >> 6;
    GEMM_PIPE(NT);

    const int crow = (wm << 7) + ((lane >> 4) << 2);
    const int ccol = (wn << 6) + (lane & 15);
    float bias_n[4];
#pragma unroll
    for (int n = 0; n < 4; ++n)
        bias_n[n] = (chunk == 0) ? b2[(e << 10) + col0 + ccol + n * 16] : 0.f;
#pragma unroll
    for (int m = 0; m < 8; ++m) {
#pragma unroll
        for (int j = 0; j < 4; ++j) {
            int r = row0 + crow + m * 16 + j;
            if (r < n_e) {
                float* dst = eo + ((size_t)(sbase + r) << 10) + col0;
#pragma unroll
                for (int n = 0; n < 4; ++n) {
                    int c = ccol + n * 16;
                    float v = acc[m][n][j] + bias_n[n];
                    if (chunk) v += dst[c];
                    dst[c] = v;
                }
            }
        }
    }
}

// ---------------- combine: out[t] = w0*eo[s0] + w1*eo[s1] (deterministic) ----------------
__global__ __launch_bounds__(256) void combine_kernel(
    const float* __restrict__ eo, const float* __restrict__ weights,
    const int* __restrict__ slot_of_tok, const int* __restrict__ base,
    float* __restrict__ out)
{
    const int t = blockIdx.x;
    const int tid = threadIdx.x;
    int s0 = slot_of_tok[t * 2], s1 = slot_of_tok[t * 2 + 1];
    int e0 = s0 >> 13, e1 = s1 >> 13;
    int c0 = base[e0] + (s0 & 8191);
    int c1 = base[e1] + (s1 & 8191);
    float w0 = weights[t * 8 + e0];
    float w1 = weights[t * 8 + e1];
    int c = tid * 4;
    f32x4 a = *(const f32x4*)(eo + ((size_t)c0 << 10) + c);
    f32x4 b = *(const f32x4*)(eo + ((size_t)c1 << 10) + c);
    f32x4 r;
    r[0] = w0 * a[0] + w1 * b[0];
    r[1] = w0 * a[1] + w1 * b[1];
    r[2] = w0 * a[2] + w1 * b[2];
    r[3] = w0 * a[3] + w1 * b[3];
    *(f32x4*)(out + ((size_t)t << 10) + c) = r;
}

extern "C" void kernel_launch(void* const* d_in, const int* in_sizes, int n_in,
                              void* d_out, int out_size, void* d_ws, size_t ws_size,
                              hipStream_t stream)
{
    const float* x      = (const float*)d_in[0];
    const float* gate_w = (const float*)d_in[1];
    const float* gate_b = (const float*)d_in[2];
    const float* w1     = (const float*)d_in[3];
    const float* b1     = (const float*)d_in[4];
    const float* w2     = (const float*)d_in[5];
    const float* b2     = (const float*)d_in[6];

    float* out         = (float*)d_out;                      // [8192,1024]
    float* weights_out = out + (size_t)T_TOK * DO_DIM;       // [8192,8]
    float* usage_out   = weights_out + (size_t)T_TOK * 8;    // [8]
    float* topi_out    = usage_out + 8;                      // [8192,2]

    char* p = (char*)d_ws;
    int* counts = (int*)p;       p += 256;
    int* base   = (int*)p;       p += 256;
    int* rbt    = (int*)p;       p += 512;                   // 1 + <=72 entries
    int* tok_list = (int*)p;     p += (size_t)8 * 8192 * 4;
    int* slot_of_tok = (int*)p;  p += (size_t)8192 * 2 * 4;
    const size_t fixed = (size_t)(p - (char*)d_ws);

    // xg 32MiB + eo 64MiB fixed; per-HC: w1t+w2t+hbuf = 65536*HC bytes
    const size_t xg_bytes = (size_t)16384 * 1024 * 2;
    const size_t eo_bytes = (size_t)16384 * 1024 * 4;
    int HC;
    if      (ws_size >= fixed + xg_bytes + eo_bytes + (size_t)65536 * 4096) HC = 4096;
    else if (ws_size >= fixed + xg_bytes + eo_bytes + (size_t)65536 * 2048) HC = 2048;
    else if (ws_size >= fixed + xg_bytes + eo_bytes + (size_t)65536 * 1024) HC = 1024;
    else                                                                    HC = 512;

    u16* xg   = (u16*)p; p += xg_bytes;
    u16* w1t  = (u16*)p; p += (size_t)8 * HC * 1024 * 2;
    u16* w2t  = (u16*)p; p += (size_t)8 * 1024 * HC * 2;
    u16* hbuf = (u16*)p; p += (size_t)16384 * HC * 2;
    float* eo = (float*)p;

    zero_counts_kernel<<<1, 64, 0, stream>>>(counts);
    gate_kernel<<<T_TOK, 256, 0, stream>>>(x, gate_w, gate_b, weights_out, topi_out,
                                           counts, tok_list, slot_of_tok);
    scan_kernel<<<1, 64, 0, stream>>>(counts, base, usage_out, rbt);
    gather_kernel<<<dim3(T_TOK, 8), 256, 0, stream>>>(x, counts, base, tok_list, xg);

    const int NC = H_DIM / HC;
    for (int c = 0; c < NC; ++c) {
        int tiles_h = HC / 64;
        transpose_kernel<<<dim3(2 * 16 * tiles_h, 1, 8), 256, 0, stream>>>(w1, w2, w1t, w2t, c, HC);
        gemm1_kernel<<<dim3(HC / 256, 80, 1), 512, 0, stream>>>(xg, w1t, b1, hbuf,
                                                                counts, base, rbt, c, HC);
        gemm2_kernel<<<dim3(DO_DIM / 256, 80, 1), 512, 0, stream>>>(hbuf, w2t, b2, eo,
                                                                    counts, base, rbt, c, HC);
    }
    combine_kernel<<<T_TOK, 256, 0, stream>>>(eo, weights_out, slot_of_tok, base, out);
}

// Round 9
// 678.341 us; speedup vs baseline: 1.0106x; 1.0106x over previous
//
#include <hip/hip_runtime.h>
#include <cstdint>
#include <cstddef>

typedef unsigned short u16;
typedef unsigned int u32;
typedef short s16x8 __attribute__((ext_vector_type(8)));   // 8 bf16 in 4 VGPRs
typedef float f32x4 __attribute__((ext_vector_type(4)));

// Problem constants: B=4,S=2048 -> T=8192 tokens, D=1024, H=4096, DO=1024, E=8, K=2
#define T_TOK 8192
#define D_IN  1024
#define H_DIM 4096
#define DO_DIM 1024

__device__ __forceinline__ u16 f2bf(float f) {  // RNE f32 -> bf16
    u32 u = __float_as_uint(f);
    return (u16)((u + 0x7FFFu + ((u >> 16) & 1u)) >> 16);
}

__device__ __forceinline__ f32x4 mfma16(s16x8 a, s16x8 b, f32x4 c) {
    return __builtin_amdgcn_mfma_f32_16x16x32_bf16(a, b, c, 0, 0, 0);
}

// async 16B global->LDS (direct DMA, no VGPR round trip)
__device__ __forceinline__ void gload16(const void* g, void* l) {
    __builtin_amdgcn_global_load_lds(
        (const __attribute__((address_space(1))) void*)g,
        (__attribute__((address_space(3))) void*)l,
        16, 0, 0);
}

// ---------------- gate: wave-per-token, shfl-butterfly reduce (no LDS, no syncthreads) ----------------
__global__ __launch_bounds__(256) void gate_kernel(
    const float* __restrict__ x, const float* __restrict__ gw,
    const float* __restrict__ gb, float* __restrict__ weights_out,
    float* __restrict__ topi_out, int* __restrict__ counts,
    int* __restrict__ tok_list, int* __restrict__ slot_of_tok)
{
    const int t = (blockIdx.x << 2) + (threadIdx.x >> 6);
    const int lane = threadIdx.x & 63;
    const float* xr = x + ((size_t)t << 10);
    float p[8];
#pragma unroll
    for (int e = 0; e < 8; ++e) p[e] = 0.f;
#pragma unroll
    for (int i = 0; i < 16; ++i) {
        int d = lane + i * 64;
        float xv = xr[d];
        const f32x4 g0 = *(const f32x4*)(gw + d * 8);
        const f32x4 g1 = *(const f32x4*)(gw + d * 8 + 4);
        p[0] += xv * g0[0]; p[1] += xv * g0[1]; p[2] += xv * g0[2]; p[3] += xv * g0[3];
        p[4] += xv * g1[0]; p[5] += xv * g1[1]; p[6] += xv * g1[2]; p[7] += xv * g1[3];
    }
#pragma unroll
    for (int off = 32; off >= 1; off >>= 1) {
#pragma unroll
        for (int e = 0; e < 8; ++e) p[e] += __shfl_xor(p[e], off, 64);
    }
    if (lane == 0) {
        float lg[8];
#pragma unroll
        for (int e = 0; e < 8; ++e) lg[e] = p[e] + gb[e];
        int i0 = 0;
        for (int e = 1; e < 8; ++e) if (lg[e] > lg[i0]) i0 = e;   // ties -> lowest idx (matches top_k)
        int i1 = (i0 == 0) ? 1 : 0;
        for (int e = 0; e < 8; ++e) if (e != i0 && lg[e] > lg[i1]) i1 = e;
        float ex = expf(lg[i1] - lg[i0]);          // <= 1
        float p0 = 1.f / (1.f + ex);
        float p1 = ex / (1.f + ex);
#pragma unroll
        for (int e = 0; e < 8; ++e)
            weights_out[t * 8 + e] = (e == i0) ? p0 : ((e == i1) ? p1 : 0.f);
        topi_out[t * 2 + 0] = (float)i0;
        topi_out[t * 2 + 1] = (float)i1;
        int pos0 = atomicAdd(&counts[i0], 1);
        tok_list[(i0 << 13) + pos0] = t;
        slot_of_tok[t * 2 + 0] = (i0 << 13) + pos0;
        int pos1 = atomicAdd(&counts[i1], 1);
        tok_list[(i1 << 13) + pos1] = t;
        slot_of_tok[t * 2 + 1] = (i1 << 13) + pos1;
    }
}

__global__ void zero_counts_kernel(int* c) { if (threadIdx.x < 8) c[threadIdx.x] = 0; }

// exclusive scan of 8 counts -> base[], usage, and dense active-row-block table
__global__ void scan_kernel(const int* __restrict__ counts, int* __restrict__ base,
                            float* __restrict__ usage_out, int* __restrict__ rbt) {
    if (threadIdx.x == 0) {
        int acc = 0;
        for (int e = 0; e < 8; ++e) {
            base[e] = acc;
            acc += counts[e];
            usage_out[e] = (float)counts[e];
        }
        int nrb = 0;
        for (int e = 0; e < 8; ++e) {
            int nb = (counts[e] + 255) >> 8;
            for (int rb = 0; rb < nb; ++rb) rbt[1 + nrb++] = (e << 16) | rb;
        }
        rbt[0] = nrb;   // <= 72
    }
}

// ---------------- gather: xg[slot][d] = bf16(x[tok][d]); grid (T,2), no wasted blocks ----------------
__global__ __launch_bounds__(256) void gather_kernel(
    const float* __restrict__ x, const int* __restrict__ slot_of_tok,
    const int* __restrict__ base, u16* __restrict__ xg)
{
    const int t = blockIdx.x;
    const int s = slot_of_tok[t * 2 + blockIdx.y];
    const int slot = base[s >> 13] + (s & 8191);
    const int d = threadIdx.x * 4;
    float4 v = *(const float4*)(x + ((size_t)t << 10) + d);
    ushort4 h;
    h.x = f2bf(v.x); h.y = f2bf(v.y); h.z = f2bf(v.z); h.w = f2bf(v.w);
    *(ushort4*)(xg + ((size_t)slot << 10) + d) = h;
}

// ---------------- transpose+cvt ----------------
__global__ __launch_bounds__(256) void transpose_kernel(
    const float* __restrict__ w1, const float* __restrict__ w2,
    u16* __restrict__ w1t, u16* __restrict__ w2t, int chunk, int HC)
{
    const int e = blockIdx.z;
    const int tid = threadIdx.x;
    const int tiles_h = HC >> 6;
    const int ntile1 = 16 * tiles_h;
    int b = blockIdx.x;
    const float* src; u16* dst;
    size_t sstride, dstride;
    int r0, c0;
    if (b < ntile1) {
        int tr = b / tiles_h, tc = b % tiles_h;
        r0 = tr * 64; c0 = tc * 64;
        src = w1 + (size_t)e * D_IN * H_DIM + (size_t)chunk * HC;
        sstride = H_DIM;
        dst = w1t + (size_t)e * HC * D_IN;
        dstride = D_IN;
    } else {
        int tb = b - ntile1;
        int tr = tb / 16, tc = tb % 16;
        r0 = tr * 64; c0 = tc * 64;
        src = w2 + ((size_t)e * H_DIM + (size_t)chunk * HC) * DO_DIM;
        sstride = DO_DIM;
        dst = w2t + (size_t)e * DO_DIM * HC;
        dstride = HC;
    }
    __shared__ u16 tile[64][68];
#pragma unroll
    for (int i = 0; i < 4; ++i) {
        int flat = i * 1024 + tid * 4;
        int rr = flat >> 6, cc = flat & 63;
        float4 v = *(const float4*)(src + (size_t)(r0 + rr) * sstride + c0 + cc);
        ushort4 h4;
        h4.x = f2bf(v.x); h4.y = f2bf(v.y); h4.z = f2bf(v.z); h4.w = f2bf(v.w);
        *(ushort4*)&tile[rr][cc] = h4;
    }
    __syncthreads();
#pragma unroll
    for (int i = 0; i < 4; ++i) {
        int flat = i * 1024 + tid * 4;
        int rr = flat >> 6, cc = flat & 63;
        ushort4 o;
        o.x = tile[cc + 0][rr]; o.y = tile[cc + 1][rr];
        o.z = tile[cc + 2][rr]; o.w = tile[cc + 3][rr];
        *(ushort4*)(dst + (size_t)(c0 + rr) * dstride + r0 + cc) = o;
    }
}

// ====================== 256x256 BK=64 8-phase MFMA GEMM cores ======================
// r9 change: MFMA path is UN-pinned — no explicit lgkmcnt(0); compiler inserts its own
// counted lgkmcnt for ds_read->MFMA (near-optimal, m97). Fences kept: counted vmcnt asm
// (staging safety — compiler can't track global_load_lds) and sched_barrier(0) AFTER each
// s_barrier (blocks cross-phase hoisting; within-phase scheduling is free).

#define STAGE_A(buf, s, kt) do { \
    char* l_ = (char*)sm + (buf)*65536 + (s)*16384 + wofs; \
    gload16(gA[2*(s)]   + (kt)*128, l_); \
    gload16(gA[2*(s)+1] + (kt)*128, l_ + 8192); } while(0)

#define STAGE_B(buf, s, kt) do { \
    char* l_ = (char*)sm + (buf)*65536 + 32768 + (s)*16384 + wofs; \
    gload16(gB[2*(s)]   + (kt)*128, l_); \
    gload16(gB[2*(s)+1] + (kt)*128, l_ + 8192); } while(0)

#define VMW4 asm volatile("s_waitcnt vmcnt(4)" ::: "memory")
#define NOWAIT do {} while(0)

#define PHASE(buf, q, RB, STAGE_STMT, WAIT_STMT) do { \
    const char* Ab_ = (const char*)sm + (buf)*65536 + (wm << 14); \
    const char* Bb_ = (const char*)sm + (buf)*65536 + 32768 + ((wn >> 1) << 14) + ((wn & 1) << 13); \
    s16x8 a0k0_ = *(const s16x8*)(Ab_ + (q)*4096 +    0 + aofs0); \
    s16x8 a0k1_ = *(const s16x8*)(Ab_ + (q)*4096 +    0 + aofs1); \
    s16x8 a1k0_ = *(const s16x8*)(Ab_ + (q)*4096 + 2048 + aofs0); \
    s16x8 a1k1_ = *(const s16x8*)(Ab_ + (q)*4096 + 2048 + aofs1); \
    if (RB) { \
        bf0[0] = *(const s16x8*)(Bb_ +    0 + aofs0); bf1[0] = *(const s16x8*)(Bb_ +    0 + aofs1); \
        bf0[1] = *(const s16x8*)(Bb_ + 2048 + aofs0); bf1[1] = *(const s16x8*)(Bb_ + 2048 + aofs1); \
        bf0[2] = *(const s16x8*)(Bb_ + 4096 + aofs0); bf1[2] = *(const s16x8*)(Bb_ + 4096 + aofs1); \
        bf0[3] = *(const s16x8*)(Bb_ + 6144 + aofs0); bf1[3] = *(const s16x8*)(Bb_ + 6144 + aofs1); \
    } \
    STAGE_STMT; \
    WAIT_STMT; \
    __builtin_amdgcn_s_barrier(); \
    __builtin_amdgcn_sched_barrier(0); \
    __builtin_amdgcn_s_setprio(1); \
    acc[(q)*2+0][0] = mfma16(a0k0_, bf0[0], acc[(q)*2+0][0]); \
    acc[(q)*2+1][0] = mfma16(a1k0_, bf0[0], acc[(q)*2+1][0]); \
    acc[(q)*2+0][1] = mfma16(a0k0_, bf0[1], acc[(q)*2+0][1]); \
    acc[(q)*2+1][1] = mfma16(a1k0_, bf0[1], acc[(q)*2+1][1]); \
    acc[(q)*2+0][2] = mfma16(a0k0_, bf0[2], acc[(q)*2+0][2]); \
    acc[(q)*2+1][2] = mfma16(a1k0_, bf0[2], acc[(q)*2+1][2]); \
    acc[(q)*2+0][3] = mfma16(a0k0_, bf0[3], acc[(q)*2+0][3]); \
    acc[(q)*2+1][3] = mfma16(a1k0_, bf0[3], acc[(q)*2+1][3]); \
    acc[(q)*2+0][0] = mfma16(a0k1_, bf1[0], acc[(q)*2+0][0]); \
    acc[(q)*2+1][0] = mfma16(a1k1_, bf1[0], acc[(q)*2+1][0]); \
    acc[(q)*2+0][1] = mfma16(a0k1_, bf1[1], acc[(q)*2+0][1]); \
    acc[(q)*2+1][1] = mfma16(a1k1_, bf1[1], acc[(q)*2+1][1]); \
    acc[(q)*2+0][2] = mfma16(a0k1_, bf1[2], acc[(q)*2+0][2]); \
    acc[(q)*2+1][2] = mfma16(a1k1_, bf1[2], acc[(q)*2+1][2]); \
    acc[(q)*2+0][3] = mfma16(a0k1_, bf1[3], acc[(q)*2+0][3]); \
    acc[(q)*2+1][3] = mfma16(a1k1_, bf1[3], acc[(q)*2+1][3]); \
    __builtin_amdgcn_s_setprio(0); \
    __builtin_amdgcn_s_barrier(); \
    __builtin_amdgcn_sched_barrier(0); } while(0)

#define GEMM_PIPE(NTV) do { \
    STAGE_B(0, 0, 0); STAGE_B(0, 1, 0); \
    STAGE_A(0, 0, 0); STAGE_A(0, 1, 0); \
    STAGE_B(1, 0, 1); STAGE_B(1, 1, 1); \
    asm volatile("s_waitcnt vmcnt(4)" ::: "memory"); \
    __builtin_amdgcn_s_barrier(); \
    __builtin_amdgcn_sched_barrier(0); \
    const int nh_ = (NTV) >> 1; \
    _Pragma("unroll 1") \
    for (int it_ = 0; it_ < nh_; ++it_) { \
        const int t_ = it_ << 1; \
        const int kA1_ = t_ + 1; \
        const int kB2_ = (t_ + 2 < (NTV)) ? t_ + 2 : (NTV) - 1; \
        const int kB3_ = (t_ + 3 < (NTV)) ? t_ + 3 : (NTV) - 1; \
        PHASE(0, 0, 1, STAGE_A(1, 0, kA1_), NOWAIT); \
        PHASE(0, 1, 0, STAGE_A(1, 1, kA1_), NOWAIT); \
        PHASE(0, 2, 0, STAGE_B(0, 0, kB2_), NOWAIT); \
        PHASE(0, 3, 0, STAGE_B(0, 1, kB2_), VMW4); \
        PHASE(1, 0, 1, STAGE_A(0, 0, kB2_), NOWAIT); \
        PHASE(1, 1, 0, STAGE_A(0, 1, kB2_), NOWAIT); \
        PHASE(1, 2, 0, STAGE_B(1, 0, kB3_), NOWAIT); \
        PHASE(1, 3, 0, STAGE_B(1, 1, kB3_), VMW4); \
    } \
    asm volatile("s_waitcnt vmcnt(0)" ::: "memory"); \
    __builtin_amdgcn_sched_barrier(0); } while(0)

// ---------------- GEMM1: hbuf[slot][hh] = relu(xg[slot] @ w1t[e] + b1[e]), bf16 out ----------------
__global__ __launch_bounds__(512) void gemm1_kernel(
    const u16* __restrict__ xg, const u16* __restrict__ w1t,
    const float* __restrict__ b1, u16* __restrict__ hbuf,
    const int* __restrict__ counts, const int* __restrict__ base,
    const int* __restrict__ rbt, int chunk, int HC)
{
    const int nrb = rbt[0];
    if (blockIdx.y >= nrb) return;
    const int ent = rbt[1 + blockIdx.y];
    const int e = ent >> 16;
    const int row0 = (ent & 0xffff) << 8;
    const int n_e = counts[e];
    const int sbase = base[e];
    const int col0 = blockIdx.x << 8;
    const int tid = threadIdx.x;
    const int lane = tid & 63;
    const int wv = tid >> 6;
    const int wm = wv >> 2;
    const int wn = wv & 3;

    __shared__ char sm[131072];

    // stage source addresses (per lane), inverse-swizzled
    const int srow = tid >> 3;
    const int scb  = ((tid & 7) << 4) ^ ((srow & 7) << 4);
    const char* gA[4]; const char* gB[4];
#pragma unroll
    for (int i = 0; i < 4; ++i) {
        int slot = sbase + row0 + i * 64 + srow;
        slot = slot < 16383 ? slot : 16383;                      // clamp tail (guarded at C-write)
        gA[i] = (const char*)xg + ((size_t)slot << 11) + scb;
        int hrow = col0 + i * 64 + srow;                         // < HC
        gB[i] = (const char*)w1t + (((size_t)e * HC + hrow) << 11) + scb;
    }
    const int wofs = __builtin_amdgcn_readfirstlane((tid >> 6) << 10);

    // fragment read offsets (swizzled)
    const int rA = lane & 15;
    const int ko = (lane >> 4) << 4;
    const int sx = (lane & 7) << 4;
    const int aofs0 = rA * 128 + (ko ^ sx);
    const int aofs1 = rA * 128 + ((64 + ko) ^ sx);

    f32x4 acc[8][4];
#pragma unroll
    for (int m = 0; m < 8; ++m)
#pragma unroll
        for (int n = 0; n < 4; ++n) acc[m][n] = f32x4{0.f, 0.f, 0.f, 0.f};
    s16x8 bf0[4], bf1[4];

    GEMM_PIPE(16);    // NT = D_IN/64

    // epilogue: bias + relu + cvt, guarded rows
    const int crow = (wm << 7) + ((lane >> 4) << 2);
    const int ccol = (wn << 6) + (lane & 15);
    float bias_n[4];
#pragma unroll
    for (int n = 0; n < 4; ++n)
        bias_n[n] = b1[(e << 12) + chunk * HC + col0 + ccol + n * 16];
#pragma unroll
    for (int m = 0; m < 8; ++m) {
#pragma unroll
        for (int j = 0; j < 4; ++j) {
            int r = row0 + crow + m * 16 + j;
            if (r < n_e) {
                u16* dst = hbuf + (size_t)(sbase + r) * HC + col0;
#pragma unroll
                for (int n = 0; n < 4; ++n) {
                    float v = acc[m][n][j] + bias_n[n];
                    v = v > 0.f ? v : 0.f;
                    dst[ccol + n * 16] = f2bf(v);
                }
            }
        }
    }
}

// ---------------- GEMM2: eo[slot][o] (+)= hbuf[slot] @ w2t[e] (+ b2 on chunk 0), f32 out ----------------
__global__ __launch_bounds__(512) void gemm2_kernel(
    const u16* __restrict__ hbuf, const u16* __restrict__ w2t,
    const float* __restrict__ b2, float* __restrict__ eo,
    const int* __restrict__ counts, const int* __restrict__ base,
    const int* __restrict__ rbt, int chunk, int HC)
{
    const int nrb = rbt[0];
    if (blockIdx.y >= nrb) return;
    const int ent = rbt[1 + blockIdx.y];
    const int e = ent >> 16;
    const int row0 = (ent & 0xffff) << 8;
    const int n_e = counts[e];
    const int sbase = base[e];
    const int col0 = blockIdx.x << 8;
    const int tid = threadIdx.x;
    const int lane = tid & 63;
    const int wv = tid >> 6;
    const int wm = wv >> 2;
    const int wn = wv & 3;

    __shared__ char sm[131072];

    const int srow = tid >> 3;
    const int scb  = ((tid & 7) << 4) ^ ((srow & 7) << 4);
    const char* gA[4]; const char* gB[4];
#pragma unroll
    for (int i = 0; i < 4; ++i) {
        int slot = sbase + row0 + i * 64 + srow;
        slot = slot < 16383 ? slot : 16383;
        gA[i] = (const char*)hbuf + (((size_t)slot * HC) << 1) + scb;
        int orow = col0 + i * 64 + srow;                          // < 1024
        gB[i] = (const char*)w2t + ((((size_t)(e << 10) + orow) * HC) << 1) + scb;
    }
    const int wofs = __builtin_amdgcn_readfirstlane((tid >> 6) << 10);

    const int rA = lane & 15;
    const int ko = (lane >> 4) << 4;
    const int sx = (lane & 7) << 4;
    const int aofs0 = rA * 128 + (ko ^ sx);
    const int aofs1 = rA * 128 + ((64 + ko) ^ sx);

    f32x4 acc[8][4];
#pragma unroll
    for (int m = 0; m < 8; ++m)
#pragma unroll
        for (int n = 0; n < 4; ++n) acc[m][n] = f32x4{0.f, 0.f, 0.f, 0.f};
    s16x8 bf0[4], bf1[4];

    const int NT = HC >> 6;
    GEMM_PIPE(NT);

    const int crow = (wm << 7) + ((lane >> 4) << 2);
    const int ccol = (wn << 6) + (lane & 15);
    float bias_n[4];
#pragma unroll
    for (int n = 0; n < 4; ++n)
        bias_n[n] = (chunk == 0) ? b2[(e << 10) + col0 + ccol + n * 16] : 0.f;
#pragma unroll
    for (int m = 0; m < 8; ++m) {
#pragma unroll
        for (int j = 0; j < 4; ++j) {
            int r = row0 + crow + m * 16 + j;
            if (r < n_e) {
                float* dst = eo + ((size_t)(sbase + r) << 10) + col0;
#pragma unroll
                for (int n = 0; n < 4; ++n) {
                    int c = ccol + n * 16;
                    float v = acc[m][n][j] + bias_n[n];
                    if (chunk) v += dst[c];
                    dst[c] = v;
                }
            }
        }
    }
}

// ---------------- combine: out[t] = w0*eo[s0] + w1*eo[s1] (deterministic) ----------------
__global__ __launch_bounds__(256) void combine_kernel(
    const float* __restrict__ eo, const float* __restrict__ weights,
    const int* __restrict__ slot_of_tok, const int* __restrict__ base,
    float* __restrict__ out)
{
    const int t = blockIdx.x;
    const int tid = threadIdx.x;
    int s0 = slot_of_tok[t * 2], s1 = slot_of_tok[t * 2 + 1];
    int e0 = s0 >> 13, e1 = s1 >> 13;
    int c0 = base[e0] + (s0 & 8191);
    int c1 = base[e1] + (s1 & 8191);
    float w0 = weights[t * 8 + e0];
    float w1 = weights[t * 8 + e1];
    int c = tid * 4;
    f32x4 a = *(const f32x4*)(eo + ((size_t)c0 << 10) + c);
    f32x4 b = *(const f32x4*)(eo + ((size_t)c1 << 10) + c);
    f32x4 r;
    r[0] = w0 * a[0] + w1 * b[0];
    r[1] = w0 * a[1] + w1 * b[1];
    r[2] = w0 * a[2] + w1 * b[2];
    r[3] = w0 * a[3] + w1 * b[3];
    *(f32x4*)(out + ((size_t)t << 10) + c) = r;
}

extern "C" void kernel_launch(void* const* d_in, const int* in_sizes, int n_in,
                              void* d_out, int out_size, void* d_ws, size_t ws_size,
                              hipStream_t stream)
{
    const float* x      = (const float*)d_in[0];
    const float* gate_w = (const float*)d_in[1];
    const float* gate_b = (const float*)d_in[2];
    const float* w1     = (const float*)d_in[3];
    const float* b1     = (const float*)d_in[4];
    const float* w2     = (const float*)d_in[5];
    const float* b2     = (const float*)d_in[6];

    float* out         = (float*)d_out;                      // [8192,1024]
    float* weights_out = out + (size_t)T_TOK * DO_DIM;       // [8192,8]
    float* usage_out   = weights_out + (size_t)T_TOK * 8;    // [8]
    float* topi_out    = usage_out + 8;                      // [8192,2]

    char* p = (char*)d_ws;
    int* counts = (int*)p;       p += 256;
    int* base   = (int*)p;       p += 256;
    int* rbt    = (int*)p;       p += 512;                   // 1 + <=72 entries
    int* tok_list = (int*)p;     p += (size_t)8 * 8192 * 4;
    int* slot_of_tok = (int*)p;  p += (size_t)8192 * 2 * 4;
    const size_t fixed = (size_t)(p - (char*)d_ws);

    // xg 32MiB + eo 64MiB fixed; per-HC: w1t+w2t+hbuf = 65536*HC bytes
    const size_t xg_bytes = (size_t)16384 * 1024 * 2;
    const size_t eo_bytes = (size_t)16384 * 1024 * 4;
    int HC;
    if      (ws_size >= fixed + xg_bytes + eo_bytes + (size_t)65536 * 4096) HC = 4096;
    else if (ws_size >= fixed + xg_bytes + eo_bytes + (size_t)65536 * 2048) HC = 2048;
    else if (ws_size >= fixed + xg_bytes + eo_bytes + (size_t)65536 * 1024) HC = 1024;
    else                                                                    HC = 512;

    u16* xg   = (u16*)p; p += xg_bytes;
    u16* w1t  = (u16*)p; p += (size_t)8 * HC * 1024 * 2;
    u16* w2t  = (u16*)p; p += (size_t)8 * 1024 * HC * 2;
    u16* hbuf = (u16*)p; p += (size_t)16384 * HC * 2;
    float* eo = (float*)p;

    zero_counts_kernel<<<1, 64, 0, stream>>>(counts);
    gate_kernel<<<T_TOK / 4, 256, 0, stream>>>(x, gate_w, gate_b, weights_out, topi_out,
                                               counts, tok_list, slot_of_tok);
    scan_kernel<<<1, 64, 0, stream>>>(counts, base, usage_out, rbt);
    gather_kernel<<<dim3(T_TOK, 2), 256, 0, stream>>>(x, slot_of_tok, base, xg);

    const int NC = H_DIM / HC;
    for (int c = 0; c < NC; ++c) {
        int tiles_h = HC / 64;
        transpose_kernel<<<dim3(2 * 16 * tiles_h, 1, 8), 256, 0, stream>>>(w1, w2, w1t, w2t, c, HC);
        gemm1_kernel<<<dim3(HC / 256, 80, 1), 512, 0, stream>>>(xg, w1t, b1, hbuf,
                                                                counts, base, rbt, c, HC);
        gemm2_kernel<<<dim3(DO_DIM / 256, 80, 1), 512, 0, stream>>>(hbuf, w2t, b2, eo,
                                                                    counts, base, rbt, c, HC);
    }
    combine_kernel<<<T_TOK, 256, 0, stream>>>(eo, weights_out, slot_of_tok, base, out);
}